// Round 1
// baseline (859.664 us; speedup 1.0000x reference)
//
#include <hip/hip_runtime.h>

// Upsample 2x via upfirdn2d([1,3,3,1] taps, factor 2), expressed as the
// dilated depthwise conv in the reference.
//   x:   (8, 64, 256, 256) fp32
//   out: (8, 64, 511, 511) fp32   [XLA dilated-conv output size: (2*255+1)+2+1-4+1]
//
// Per output pixel, only 2 taps/dim land on non-zero dilated positions:
//   even o: inputs rows (o/2 - 1, o/2),     per-dim weights (k3, k1) * 2/sum
//   odd  o: inputs rows (o>>1,   o>>1 + 1), per-dim weights (k2, k0) * 2/sum
// 2D weight = product of per-dim weights. Only o==0 can index row/col -1 (zero pad).

#define IN_H 256
#define IN_W 256
#define OUT_H 511
#define OUT_W 511
#define N_BC (8 * 64)

__global__ __launch_bounds__(256) void Upsample_64948495450678_kernel(
    const float* __restrict__ x,
    const float* __restrict__ k1d,
    float* __restrict__ out)
{
    const int ow = blockIdx.x * 256 + threadIdx.x;
    if (ow >= OUT_W) return;
    const int oh = blockIdx.y;
    const int bc = blockIdx.z;

    // Build per-dim tap weights from the actual kernel input (uniform per thread;
    // scalar-cached loads). k2d = outer(k)/sum(outer) * 4  ->  per-dim scale 2/sum(k).
    const float k0 = k1d[0], k1 = k1d[1], k2 = k1d[2], k3 = k1d[3];
    const float inv = 2.0f / (k0 + k1 + k2 + k3);

    const int oy = oh & 1;
    const int ox = ow & 1;
    const float wy0 = (oy ? k2 : k3) * inv;
    const float wy1 = (oy ? k0 : k1) * inv;
    const float wx0 = (ox ? k2 : k3) * inv;
    const float wx1 = (ox ? k0 : k1) * inv;

    const int r = (oh >> 1) + oy - 1;   // top input row; r+1 always <= 255
    const int c = (ow >> 1) + ox - 1;   // left input col; c+1 always <= 255

    const float* __restrict__ xp = x + (size_t)bc * (IN_H * IN_W);

    const bool rv = (r >= 0);
    const bool cv = (c >= 0);

    float v00 = 0.0f, v01 = 0.0f, v10 = 0.0f, v11 = 0.0f;
    const float* row0 = xp + (size_t)(rv ? r : 0) * IN_W;
    const float* row1 = xp + (size_t)(r + 1) * IN_W;
    if (rv) {
        if (cv) v00 = row0[c];
        v01 = row0[c + 1];
    }
    if (cv) v10 = row1[c];
    v11 = row1[c + 1];

    const float result = wy0 * (wx0 * v00 + wx1 * v01)
                       + wy1 * (wx0 * v10 + wx1 * v11);

    out[((size_t)bc * OUT_H + oh) * OUT_W + ow] = result;
}

extern "C" void kernel_launch(void* const* d_in, const int* in_sizes, int n_in,
                              void* d_out, int out_size, void* d_ws, size_t ws_size,
                              hipStream_t stream) {
    const float* x   = (const float*)d_in[0];
    const float* k1d = (const float*)d_in[1];
    float* out = (float*)d_out;

    dim3 block(256, 1, 1);
    dim3 grid((OUT_W + 255) / 256, OUT_H, N_BC);
    Upsample_64948495450678_kernel<<<grid, block, 0, stream>>>(x, k1d, out);
}